// Round 12
// baseline (1354.481 us; speedup 1.0000x reference)
//
#include <hip/hip_runtime.h>

#define NN 100000
#define NE 1600000
#define H  128
#define SCAN_CHUNK 512
#define NB_SCAN ((NN + SCAN_CHUNK - 1) / SCAN_CHUNK)   // 196

// ---------------- zero int array ----------------
__global__ void zero_int(int* __restrict__ p, int n) {
    int i = blockIdx.x * blockDim.x + threadIdx.x;
    if (i < n) p[i] = 0;
}

// ---------------- histogram of dst ----------------
__global__ void hist_kernel(const int* __restrict__ ei, int* __restrict__ deg) {
    int e = blockIdx.x * 256 + threadIdx.x;
    if (e < NE) atomicAdd(&deg[ei[NE + e]], 1);
}

// ---------------- per-chunk exclusive scan ----------------
__global__ __launch_bounds__(SCAN_CHUNK) void scan_block(const int* __restrict__ deg,
                                                         int* __restrict__ off,
                                                         int* __restrict__ sums, int n) {
    __shared__ int buf[SCAN_CHUNK];
    int base = blockIdx.x * SCAN_CHUNK;
    int t = threadIdx.x;
    int v = (base + t < n) ? deg[base + t] : 0;
    buf[t] = v;
    __syncthreads();
    for (int s = 1; s < SCAN_CHUNK; s <<= 1) {
        int add = (t >= s) ? buf[t - s] : 0;
        __syncthreads();
        buf[t] += add;
        __syncthreads();
    }
    if (base + t < n) off[base + t] = buf[t] - v;
    if (t == SCAN_CHUNK - 1) sums[blockIdx.x] = buf[t];
}

__global__ __launch_bounds__(256) void scan_sums(int* __restrict__ sums, int nb) {
    __shared__ int buf[256];
    int t = threadIdx.x;
    int v = (t < nb) ? sums[t] : 0;
    buf[t] = v;
    __syncthreads();
    for (int s = 1; s < 256; s <<= 1) {
        int add = (t >= s) ? buf[t - s] : 0;
        __syncthreads();
        buf[t] += add;
        __syncthreads();
    }
    if (t < nb) sums[t] = buf[t] - v;
}

__global__ void scan_add(int* __restrict__ off, const int* __restrict__ sums,
                         int* __restrict__ cur, int n) {
    int i = blockIdx.x * 256 + threadIdx.x;
    if (i < n) {
        int v = off[i] + sums[i >> 9];
        off[i] = v;
        cur[i] = v;
    }
}

// ---------------- fill CSR: pack (local_row<<20 | src, weight) ----------------
// local_row = dst & 15 (blocks of 16 rows, 16-aligned). src < 2^17 fits in 20 bits.
__global__ void fill_kernel(const int* __restrict__ ei, const float* __restrict__ ew,
                            int* __restrict__ cur, int2* __restrict__ csr) {
    int e = blockIdx.x * 256 + threadIdx.x;
    if (e >= NE) return;
    int d = ei[NE + e];
    int pos = atomicAdd(&cur[d], 1);
    csr[pos] = make_int2(((d & 15) << 20) | ei[e], __float_as_int(ew[e]));
}

// ---------------- convert W_edge f32 -> packed bf16 (RNE) ----------------
__global__ void conv_bf16(const float* __restrict__ in, unsigned int* __restrict__ outp,
                          int n2) {
    int i = blockIdx.x * 256 + threadIdx.x;
    if (i >= n2) return;
    float2 v = *reinterpret_cast<const float2*>(&in[(long long)i * 2]);
    unsigned int b0 = __float_as_uint(v.x);
    unsigned int b1 = __float_as_uint(v.y);
    b0 = (b0 + 0x7fffu + ((b0 >> 16) & 1u)) >> 16;
    b1 = (b1 + 0x7fffu + ((b1 >> 16) & 1u)) >> 16;
    outp[i] = b0 | (b1 << 16);
}

// ---- merged precompute: blocks 0..127 -> W3 rows; block 128 -> b4 ----
__global__ __launch_bounds__(128) void precompute_all(const float* __restrict__ W_node,
                                                      const float* __restrict__ W_cat2,
                                                      const float* __restrict__ b_edge,
                                                      const float* __restrict__ W_cat1,
                                                      const float* __restrict__ b_node,
                                                      const float* __restrict__ b_cat1,
                                                      const float* __restrict__ b_cat2,
                                                      float* __restrict__ W3,
                                                      float* __restrict__ b4) {
    int c = threadIdx.x;
    if (blockIdx.x < H) {
        int k = blockIdx.x;
        __shared__ float wrow[H];
        wrow[c] = W_node[k * H + c];
        __syncthreads();
        float acc = wrow[c];   // identity part of (I + W_cat2)
        #pragma unroll 8
        for (int j = 0; j < H; ++j)
            acc += wrow[j] * W_cat2[j * H + c];
        W3[k * H + c] = acc;
    } else {
        __shared__ float be[H], bn[H];
        be[c] = b_edge[c];
        bn[c] = b_node[c];
        __syncthreads();
        float acc = be[c] + bn[c] + b_cat1[c] + b_cat2[c];
        for (int j = 0; j < H; ++j)
            acc += be[j] * W_cat1[j * H + c] + bn[j] * W_cat2[j * H + c];
        b4[c] = acc;
    }
}

// ------- fully fused: FLAT-EDGE gather (scalar csr path + ds_add_f32) + B + relu + C -------
// Block owns rows [16b,16b+16) whose CSR range [off[row0], off[row0+16)) is contiguous.
// Waves iterate uniform 8-edge chunks: csr entries via scalar loads (src/w/row in SGPRs),
// 8 independent wbf loads (SGPR base + constant lane voffset), LDS-atomic accumulate.
__global__ __launch_bounds__(256) void gather_fused(const int* __restrict__ off,
                                                    const int2* __restrict__ csr,
                                                    const unsigned int* __restrict__ wbf,
                                                    const float* __restrict__ x,
                                                    const float* __restrict__ Wc1,
                                                    const float* __restrict__ W3,
                                                    const float* __restrict__ b4,
                                                    const float* __restrict__ Wf,
                                                    const float* __restrict__ bf,
                                                    float* __restrict__ out,
                                                    int nrows) {
    const int TR = 16;
    __shared__ float As[TR][H];
    __shared__ float Xs[TR][H];
    int row0 = blockIdx.x * TR;
    int tid = threadIdx.x;

    // zero As, load Xs
    for (int i = tid; i < TR * H / 4; i += 256) {
        int fi = i * 4;
        int rr = fi >> 7, cc = fi & 127;
        float4 xv = {0.f, 0.f, 0.f, 0.f};
        *reinterpret_cast<float4*>(&As[rr][cc]) = xv;
        if (row0 + rr < nrows)
            xv = *reinterpret_cast<const float4*>(&x[(long long)(row0 + rr) * H + cc]);
        *reinterpret_cast<float4*>(&Xs[rr][cc]) = xv;
    }
    __syncthreads();

    // ---- phase A: flat-edge gather over [s0, s1) ----
    int lane = tid & 63;
    int wvu  = __builtin_amdgcn_readfirstlane(tid >> 6);          // wave id, uniform
    int s0u  = __builtin_amdgcn_readfirstlane(off[row0]);
    int s1u  = (row0 + TR < nrows) ? __builtin_amdgcn_readfirstlane(off[row0 + TR]) : NE;

    int b = s0u + wvu * 8;
    for (; b + 8 <= s1u; b += 32) {
        #pragma unroll
        for (int u = 0; u < 8; ++u) {
            int2 e = csr[b + u];                    // uniform -> s_load
            float w = __int_as_float(e.y);
            int lr  = e.x >> 20;                    // local row (0..15)
            int src = e.x & 0xFFFFF;
            unsigned int uv = wbf[(long long)src * 64 + lane];
            atomicAdd(&As[lr][2 * lane],     w * __uint_as_float(uv << 16));
            atomicAdd(&As[lr][2 * lane + 1], w * __uint_as_float(uv & 0xffff0000u));
        }
    }
    int bend = (b + 8 < s1u) ? b + 8 : s1u;         // wave's partial tail chunk
    for (int j = b; j < bend; ++j) {
        int2 e = csr[j];
        float w = __int_as_float(e.y);
        int lr  = e.x >> 20;
        int src = e.x & 0xFFFFF;
        unsigned int uv = wbf[(long long)src * 64 + lane];
        atomicAdd(&As[lr][2 * lane],     w * __uint_as_float(uv << 16));
        atomicAdd(&As[lr][2 * lane + 1], w * __uint_as_float(uv & 0xffff0000u));
    }
    __syncthreads();

    // ---- phase B: t4 = agg + agg@Wc1 + x@W3 + b4 (R8 row-sliced, conflict-free) ----
    int c2 = (tid & 63) * 2;
    int rbase = (tid >> 6) * 4;
    float2 b4v = *reinterpret_cast<const float2*>(&b4[c2]);
    float acc[4][2];
    #pragma unroll
    for (int r = 0; r < 4; ++r) {
        acc[r][0] = As[rbase + r][c2]     + b4v.x;   // identity term of (I + W_cat1)
        acc[r][1] = As[rbase + r][c2 + 1] + b4v.y;
    }

    for (int k = 0; k < H; k += 4) {
        float2 w1[4], w3[4];
        #pragma unroll
        for (int kk = 0; kk < 4; ++kk) {
            w1[kk] = *reinterpret_cast<const float2*>(&Wc1[(k + kk) * H + c2]);
            w3[kk] = *reinterpret_cast<const float2*>(&W3[(k + kk) * H + c2]);
        }
        #pragma unroll
        for (int r = 0; r < 4; ++r) {
            float4 a  = *reinterpret_cast<const float4*>(&As[rbase + r][k]);
            float4 xv = *reinterpret_cast<const float4*>(&Xs[rbase + r][k]);
            acc[r][0] += a.x * w1[0].x + a.y * w1[1].x + a.z * w1[2].x + a.w * w1[3].x
                       + xv.x * w3[0].x + xv.y * w3[1].x + xv.z * w3[2].x + xv.w * w3[3].x;
            acc[r][1] += a.x * w1[0].y + a.y * w1[1].y + a.z * w1[2].y + a.w * w1[3].y
                       + xv.x * w3[0].y + xv.y * w3[1].y + xv.z * w3[2].y + xv.w * w3[3].y;
        }
    }

    // ---- relu, stash back to LDS ----
    __syncthreads();
    #pragma unroll
    for (int r = 0; r < 4; ++r) {
        As[rbase + r][c2]     = fmaxf(acc[r][0], 0.f);
        As[rbase + r][c2 + 1] = fmaxf(acc[r][1], 0.f);
    }
    __syncthreads();

    // ---- phase C: out = relu(t4) @ Wf + bf ----
    float2 bfv = *reinterpret_cast<const float2*>(&bf[c2]);
    float acc2[4][2];
    #pragma unroll
    for (int r = 0; r < 4; ++r) {
        acc2[r][0] = bfv.x;
        acc2[r][1] = bfv.y;
    }

    for (int k = 0; k < H; k += 4) {
        float2 wf[4];
        #pragma unroll
        for (int kk = 0; kk < 4; ++kk)
            wf[kk] = *reinterpret_cast<const float2*>(&Wf[(k + kk) * H + c2]);
        #pragma unroll
        for (int r = 0; r < 4; ++r) {
            float4 v = *reinterpret_cast<const float4*>(&As[rbase + r][k]);
            acc2[r][0] += v.x * wf[0].x + v.y * wf[1].x + v.z * wf[2].x + v.w * wf[3].x;
            acc2[r][1] += v.x * wf[0].y + v.y * wf[1].y + v.z * wf[2].y + v.w * wf[3].y;
        }
    }

    #pragma unroll
    for (int r = 0; r < 4; ++r) {
        int row = row0 + rbase + r;
        if (row < nrows) {
            float2 o{acc2[r][0], acc2[r][1]};
            *reinterpret_cast<float2*>(&out[(long long)row * H + c2]) = o;
        }
    }
}

extern "C" void kernel_launch(void* const* d_in, const int* in_sizes, int n_in,
                              void* d_out, int out_size, void* d_ws, size_t ws_size,
                              hipStream_t stream) {
    const float* x       = (const float*)d_in[0];
    const int*   ei      = (const int*)d_in[1];
    const float* ew      = (const float*)d_in[2];
    const float* W_edge  = (const float*)d_in[3];
    const float* b_edge  = (const float*)d_in[4];
    const float* W_node  = (const float*)d_in[5];
    const float* b_node  = (const float*)d_in[6];
    const float* W_cat1  = (const float*)d_in[7];
    const float* b_cat1  = (const float*)d_in[8];
    const float* W_cat2  = (const float*)d_in[9];
    const float* b_cat2  = (const float*)d_in[10];
    const float* W_final = (const float*)d_in[11];
    const float* b_final = (const float*)d_in[12];
    float* out = (float*)d_out;

    // workspace layout
    int*  deg  = (int*)d_ws;                         // NN
    int*  off  = deg + NN;                           // NN
    int*  cur  = off + NN;                           // NN
    int*  sums = cur + NN;                           // 512
    int2* csr  = (int2*)(sums + 512);                // NE   (8B aligned: offset 1202048)
    unsigned int* wbf = (unsigned int*)(csr + NE);   // NN*64 packed bf16 pairs (25.6 MB)
    float* W3  = (float*)(wbf + (size_t)NN * 64);    // H*H
    float* b4  = W3 + H * H;                         // H

    // 1. CSR build
    zero_int<<<(NN + 255) / 256, 256, 0, stream>>>(deg, NN);
    hist_kernel<<<(NE + 255) / 256, 256, 0, stream>>>(ei, deg);
    scan_block<<<NB_SCAN, SCAN_CHUNK, 0, stream>>>(deg, off, sums, NN);
    scan_sums<<<1, 256, 0, stream>>>(sums, NB_SCAN);
    scan_add<<<(NN + 255) / 256, 256, 0, stream>>>(off, sums, cur, NN);
    fill_kernel<<<(NE + 255) / 256, 256, 0, stream>>>(ei, ew, cur, csr);

    // 2. W_edge -> bf16, merged precompute (W3 + b4)
    conv_bf16<<<(NN * H / 2 + 255) / 256, 256, 0, stream>>>(W_edge, wbf, NN * H / 2);
    precompute_all<<<H + 1, H, 0, stream>>>(W_node, W_cat2, b_edge, W_cat1,
                                            b_node, b_cat1, b_cat2, W3, b4);

    // 3. fully fused flat-edge gather + affine + relu + final linear -> d_out
    gather_fused<<<(NN + 15) / 16, 256, 0, stream>>>(off, csr, wbf, x,
                                                     W_cat1, W3, b4,
                                                     W_final, b_final, out, NN);
}

// Round 13
// 474.602 us; speedup vs baseline: 2.8539x; 2.8539x over previous
//
#include <hip/hip_runtime.h>

#define NN 100000
#define NE 1600000
#define H  128
#define SCAN_CHUNK 512
#define NB_SCAN ((NN + SCAN_CHUNK - 1) / SCAN_CHUNK)   // 196

// ---------------- zero int array ----------------
__global__ void zero_int(int* __restrict__ p, int n) {
    int i = blockIdx.x * blockDim.x + threadIdx.x;
    if (i < n) p[i] = 0;
}

// ---------------- histogram of dst ----------------
__global__ void hist_kernel(const int* __restrict__ ei, int* __restrict__ deg) {
    int e = blockIdx.x * 256 + threadIdx.x;
    if (e < NE) atomicAdd(&deg[ei[NE + e]], 1);
}

// ---------------- per-chunk exclusive scan ----------------
__global__ __launch_bounds__(SCAN_CHUNK) void scan_block(const int* __restrict__ deg,
                                                         int* __restrict__ off,
                                                         int* __restrict__ sums, int n) {
    __shared__ int buf[SCAN_CHUNK];
    int base = blockIdx.x * SCAN_CHUNK;
    int t = threadIdx.x;
    int v = (base + t < n) ? deg[base + t] : 0;
    buf[t] = v;
    __syncthreads();
    for (int s = 1; s < SCAN_CHUNK; s <<= 1) {
        int add = (t >= s) ? buf[t - s] : 0;
        __syncthreads();
        buf[t] += add;
        __syncthreads();
    }
    if (base + t < n) off[base + t] = buf[t] - v;
    if (t == SCAN_CHUNK - 1) sums[blockIdx.x] = buf[t];
}

__global__ __launch_bounds__(256) void scan_sums(int* __restrict__ sums, int nb) {
    __shared__ int buf[256];
    int t = threadIdx.x;
    int v = (t < nb) ? sums[t] : 0;
    buf[t] = v;
    __syncthreads();
    for (int s = 1; s < 256; s <<= 1) {
        int add = (t >= s) ? buf[t - s] : 0;
        __syncthreads();
        buf[t] += add;
        __syncthreads();
    }
    if (t < nb) sums[t] = buf[t] - v;
}

__global__ void scan_add(int* __restrict__ off, const int* __restrict__ sums,
                         int* __restrict__ cur, int n) {
    int i = blockIdx.x * 256 + threadIdx.x;
    if (i < n) {
        int v = off[i] + sums[i >> 9];
        off[i] = v;
        cur[i] = v;
    }
}

// ---------------- fill CSR with packed (src, weight) ----------------
__global__ void fill_kernel(const int* __restrict__ ei, const float* __restrict__ ew,
                            int* __restrict__ cur, int2* __restrict__ csr) {
    int e = blockIdx.x * 256 + threadIdx.x;
    if (e >= NE) return;
    int d = ei[NE + e];
    int pos = atomicAdd(&cur[d], 1);
    csr[pos] = make_int2(ei[e], __float_as_int(ew[e]));
}

// ---------------- convert W_edge f32 -> packed bf16 (RNE) ----------------
__global__ void conv_bf16(const float* __restrict__ in, unsigned int* __restrict__ outp,
                          int n2) {
    int i = blockIdx.x * 256 + threadIdx.x;
    if (i >= n2) return;
    float2 v = *reinterpret_cast<const float2*>(&in[(long long)i * 2]);
    unsigned int b0 = __float_as_uint(v.x);
    unsigned int b1 = __float_as_uint(v.y);
    b0 = (b0 + 0x7fffu + ((b0 >> 16) & 1u)) >> 16;
    b1 = (b1 + 0x7fffu + ((b1 >> 16) & 1u)) >> 16;
    outp[i] = b0 | (b1 << 16);
}

// ---- merged precompute: blocks 0..127 -> W3 rows; block 128 -> b4 ----
__global__ __launch_bounds__(128) void precompute_all(const float* __restrict__ W_node,
                                                      const float* __restrict__ W_cat2,
                                                      const float* __restrict__ b_edge,
                                                      const float* __restrict__ W_cat1,
                                                      const float* __restrict__ b_node,
                                                      const float* __restrict__ b_cat1,
                                                      const float* __restrict__ b_cat2,
                                                      float* __restrict__ W3,
                                                      float* __restrict__ b4) {
    int c = threadIdx.x;
    if (blockIdx.x < H) {
        int k = blockIdx.x;
        __shared__ float wrow[H];
        wrow[c] = W_node[k * H + c];
        __syncthreads();
        float acc = wrow[c];   // identity part of (I + W_cat2)
        #pragma unroll 8
        for (int j = 0; j < H; ++j)
            acc += wrow[j] * W_cat2[j * H + c];
        W3[k * H + c] = acc;
    } else {
        __shared__ float be[H], bn[H];
        be[c] = b_edge[c];
        bn[c] = b_node[c];
        __syncthreads();
        float acc = be[c] + bn[c] + b_cat1[c] + b_cat2[c];
        for (int j = 0; j < H; ++j)
            acc += be[j] * W_cat1[j * H + c] + bn[j] * W_cat2[j * H + c];
        b4[c] = acc;
    }
}

// ------- fully fused, TR=32 rows/block, 256 threads, 8 rows/thread in B/C -------
// Gather: R8 form (per-row CSR walk, bf16 rows, scalar bounds), 8 rows per wave.
// Phases B/C: row-sliced (conflict-free); each thread owns cols {c2,c2+1} x 8 rows,
// so each 8-float2 weight-load group feeds 128 FMAs (2x the R8 amortization).
__global__ __launch_bounds__(256) void gather_fused(const int* __restrict__ off,
                                                    const int* __restrict__ end,
                                                    const int2* __restrict__ csr,
                                                    const unsigned int* __restrict__ wbf,
                                                    const float* __restrict__ x,
                                                    const float* __restrict__ Wc1,
                                                    const float* __restrict__ W3,
                                                    const float* __restrict__ b4,
                                                    const float* __restrict__ Wf,
                                                    const float* __restrict__ bf,
                                                    float* __restrict__ out,
                                                    int nrows) {
    const int TR = 32;
    __shared__ float As[TR][H];
    __shared__ float Xs[TR][H];
    int row0 = blockIdx.x * TR;
    int tid = threadIdx.x;

    // load Xs (x rows): 32*128/4 = 1024 float4 over 256 threads
    for (int i = tid; i < TR * H / 4; i += 256) {
        int fi = i * 4;
        int rr = fi >> 7, cc = fi & 127;
        float4 xv = {0.f, 0.f, 0.f, 0.f};
        if (row0 + rr < nrows)
            xv = *reinterpret_cast<const float4*>(&x[(long long)(row0 + rr) * H + cc]);
        *reinterpret_cast<float4*>(&Xs[rr][cc]) = xv;
    }

    // ---- phase A: gather (bf16 rows). wave w handles rows 8w..8w+7 ----
    int wv = tid >> 6;
    int lane = tid & 63;
    #pragma unroll
    for (int rr8 = 0; rr8 < 8; ++rr8) {
        int rr = wv * 8 + rr8;
        int d = row0 + rr;
        float ax = 0.f, ay = 0.f;
        if (d < nrows) {
            int i0 = __builtin_amdgcn_readfirstlane(off[d]);
            int i1 = __builtin_amdgcn_readfirstlane(end[d]);
            int j = i0;
            for (; j + 4 <= i1; j += 4) {
                int2 e0 = csr[j];
                int2 e1 = csr[j + 1];
                int2 e2 = csr[j + 2];
                int2 e3 = csr[j + 3];
                unsigned int u0 = wbf[(long long)e0.x * 64 + lane];
                unsigned int u1 = wbf[(long long)e1.x * 64 + lane];
                unsigned int u2 = wbf[(long long)e2.x * 64 + lane];
                unsigned int u3 = wbf[(long long)e3.x * 64 + lane];
                float w0 = __int_as_float(e0.y), w1 = __int_as_float(e1.y);
                float w2 = __int_as_float(e2.y), w3 = __int_as_float(e3.y);
                ax += w0 * __uint_as_float(u0 << 16) + w1 * __uint_as_float(u1 << 16)
                    + w2 * __uint_as_float(u2 << 16) + w3 * __uint_as_float(u3 << 16);
                ay += w0 * __uint_as_float(u0 & 0xffff0000u) + w1 * __uint_as_float(u1 & 0xffff0000u)
                    + w2 * __uint_as_float(u2 & 0xffff0000u) + w3 * __uint_as_float(u3 & 0xffff0000u);
            }
            for (; j < i1; ++j) {
                int2 e = csr[j];
                float w = __int_as_float(e.y);
                unsigned int u = wbf[(long long)e.x * 64 + lane];
                ax += w * __uint_as_float(u << 16);
                ay += w * __uint_as_float(u & 0xffff0000u);
            }
        }
        *reinterpret_cast<float2*>(&As[rr][lane * 2]) = make_float2(ax, ay);
    }
    __syncthreads();

    // ---- phase B: t4 = agg + agg@Wc1 + x@W3 + b4 (8 rows/thread) ----
    int c2 = (tid & 63) * 2;
    int rbase = (tid >> 6) * 8;
    float2 b4v = *reinterpret_cast<const float2*>(&b4[c2]);
    float acc[8][2];
    #pragma unroll
    for (int r = 0; r < 8; ++r) {
        acc[r][0] = As[rbase + r][c2]     + b4v.x;   // identity term of (I + W_cat1)
        acc[r][1] = As[rbase + r][c2 + 1] + b4v.y;
    }

    for (int k = 0; k < H; k += 4) {
        float2 w1[4], w3[4];
        #pragma unroll
        for (int kk = 0; kk < 4; ++kk) {
            w1[kk] = *reinterpret_cast<const float2*>(&Wc1[(k + kk) * H + c2]);
            w3[kk] = *reinterpret_cast<const float2*>(&W3[(k + kk) * H + c2]);
        }
        #pragma unroll
        for (int r = 0; r < 8; ++r) {
            float4 a  = *reinterpret_cast<const float4*>(&As[rbase + r][k]);
            float4 xv = *reinterpret_cast<const float4*>(&Xs[rbase + r][k]);
            acc[r][0] += a.x * w1[0].x + a.y * w1[1].x + a.z * w1[2].x + a.w * w1[3].x
                       + xv.x * w3[0].x + xv.y * w3[1].x + xv.z * w3[2].x + xv.w * w3[3].x;
            acc[r][1] += a.x * w1[0].y + a.y * w1[1].y + a.z * w1[2].y + a.w * w1[3].y
                       + xv.x * w3[0].y + xv.y * w3[1].y + xv.z * w3[2].y + xv.w * w3[3].y;
        }
    }

    // ---- relu, stash back to LDS ----
    __syncthreads();
    #pragma unroll
    for (int r = 0; r < 8; ++r) {
        As[rbase + r][c2]     = fmaxf(acc[r][0], 0.f);
        As[rbase + r][c2 + 1] = fmaxf(acc[r][1], 0.f);
    }
    __syncthreads();

    // ---- phase C: out = relu(t4) @ Wf + bf ----
    float2 bfv = *reinterpret_cast<const float2*>(&bf[c2]);
    float acc2[8][2];
    #pragma unroll
    for (int r = 0; r < 8; ++r) {
        acc2[r][0] = bfv.x;
        acc2[r][1] = bfv.y;
    }

    for (int k = 0; k < H; k += 4) {
        float2 wf[4];
        #pragma unroll
        for (int kk = 0; kk < 4; ++kk)
            wf[kk] = *reinterpret_cast<const float2*>(&Wf[(k + kk) * H + c2]);
        #pragma unroll
        for (int r = 0; r < 8; ++r) {
            float4 v = *reinterpret_cast<const float4*>(&As[rbase + r][k]);
            acc2[r][0] += v.x * wf[0].x + v.y * wf[1].x + v.z * wf[2].x + v.w * wf[3].x;
            acc2[r][1] += v.x * wf[0].y + v.y * wf[1].y + v.z * wf[2].y + v.w * wf[3].y;
        }
    }

    #pragma unroll
    for (int r = 0; r < 8; ++r) {
        int row = row0 + rbase + r;
        if (row < nrows) {
            float2 o{acc2[r][0], acc2[r][1]};
            *reinterpret_cast<float2*>(&out[(long long)row * H + c2]) = o;
        }
    }
}

extern "C" void kernel_launch(void* const* d_in, const int* in_sizes, int n_in,
                              void* d_out, int out_size, void* d_ws, size_t ws_size,
                              hipStream_t stream) {
    const float* x       = (const float*)d_in[0];
    const int*   ei      = (const int*)d_in[1];
    const float* ew      = (const float*)d_in[2];
    const float* W_edge  = (const float*)d_in[3];
    const float* b_edge  = (const float*)d_in[4];
    const float* W_node  = (const float*)d_in[5];
    const float* b_node  = (const float*)d_in[6];
    const float* W_cat1  = (const float*)d_in[7];
    const float* b_cat1  = (const float*)d_in[8];
    const float* W_cat2  = (const float*)d_in[9];
    const float* b_cat2  = (const float*)d_in[10];
    const float* W_final = (const float*)d_in[11];
    const float* b_final = (const float*)d_in[12];
    float* out = (float*)d_out;

    // workspace layout
    int*  deg  = (int*)d_ws;                         // NN
    int*  off  = deg + NN;                           // NN
    int*  cur  = off + NN;                           // NN
    int*  sums = cur + NN;                           // 512
    int2* csr  = (int2*)(sums + 512);                // NE   (8B aligned: offset 1202048)
    unsigned int* wbf = (unsigned int*)(csr + NE);   // NN*64 packed bf16 pairs (25.6 MB)
    float* W3  = (float*)(wbf + (size_t)NN * 64);    // H*H
    float* b4  = W3 + H * H;                         // H

    // 1. CSR build
    zero_int<<<(NN + 255) / 256, 256, 0, stream>>>(deg, NN);
    hist_kernel<<<(NE + 255) / 256, 256, 0, stream>>>(ei, deg);
    scan_block<<<NB_SCAN, SCAN_CHUNK, 0, stream>>>(deg, off, sums, NN);
    scan_sums<<<1, 256, 0, stream>>>(sums, NB_SCAN);
    scan_add<<<(NN + 255) / 256, 256, 0, stream>>>(off, sums, cur, NN);
    fill_kernel<<<(NE + 255) / 256, 256, 0, stream>>>(ei, ew, cur, csr);

    // 2. W_edge -> bf16, merged precompute (W3 + b4)
    conv_bf16<<<(NN * H / 2 + 255) / 256, 256, 0, stream>>>(W_edge, wbf, NN * H / 2);
    precompute_all<<<H + 1, H, 0, stream>>>(W_node, W_cat2, b_edge, W_cat1,
                                            b_node, b_cat1, b_cat2, W3, b4);

    // 3. fully fused gather + affine + relu + final linear -> d_out
    gather_fused<<<(NN + 31) / 32, 256, 0, stream>>>(off, cur, csr, wbf, x,
                                                     W_cat1, W3, b4,
                                                     W_final, b_final, out, NN);
}

// Round 14
// 444.875 us; speedup vs baseline: 3.0446x; 1.0668x over previous
//
#include <hip/hip_runtime.h>

#define NN 100000
#define NE 1600000
#define H  128
#define SCAN_CHUNK 512
#define NB_SCAN ((NN + SCAN_CHUNK - 1) / SCAN_CHUNK)   // 196

// ---------------- zero int array ----------------
__global__ void zero_int(int* __restrict__ p, int n) {
    int i = blockIdx.x * blockDim.x + threadIdx.x;
    if (i < n) p[i] = 0;
}

// ---------------- histogram of dst ----------------
__global__ void hist_kernel(const int* __restrict__ ei, int* __restrict__ deg) {
    int e = blockIdx.x * 256 + threadIdx.x;
    if (e < NE) atomicAdd(&deg[ei[NE + e]], 1);
}

// ---------------- per-chunk exclusive scan ----------------
__global__ __launch_bounds__(SCAN_CHUNK) void scan_block(const int* __restrict__ deg,
                                                         int* __restrict__ off,
                                                         int* __restrict__ sums, int n) {
    __shared__ int buf[SCAN_CHUNK];
    int base = blockIdx.x * SCAN_CHUNK;
    int t = threadIdx.x;
    int v = (base + t < n) ? deg[base + t] : 0;
    buf[t] = v;
    __syncthreads();
    for (int s = 1; s < SCAN_CHUNK; s <<= 1) {
        int add = (t >= s) ? buf[t - s] : 0;
        __syncthreads();
        buf[t] += add;
        __syncthreads();
    }
    if (base + t < n) off[base + t] = buf[t] - v;
    if (t == SCAN_CHUNK - 1) sums[blockIdx.x] = buf[t];
}

__global__ __launch_bounds__(256) void scan_sums(int* __restrict__ sums, int nb) {
    __shared__ int buf[256];
    int t = threadIdx.x;
    int v = (t < nb) ? sums[t] : 0;
    buf[t] = v;
    __syncthreads();
    for (int s = 1; s < 256; s <<= 1) {
        int add = (t >= s) ? buf[t - s] : 0;
        __syncthreads();
        buf[t] += add;
        __syncthreads();
    }
    if (t < nb) sums[t] = buf[t] - v;
}

__global__ void scan_add(int* __restrict__ off, const int* __restrict__ sums,
                         int* __restrict__ cur, int n) {
    int i = blockIdx.x * 256 + threadIdx.x;
    if (i < n) {
        int v = off[i] + sums[i >> 9];
        off[i] = v;
        cur[i] = v;
    }
}

// ---------------- fill CSR with packed (src, weight) ----------------
__global__ void fill_kernel(const int* __restrict__ ei, const float* __restrict__ ew,
                            int* __restrict__ cur, int2* __restrict__ csr) {
    int e = blockIdx.x * 256 + threadIdx.x;
    if (e >= NE) return;
    int d = ei[NE + e];
    int pos = atomicAdd(&cur[d], 1);
    csr[pos] = make_int2(ei[e], __float_as_int(ew[e]));
}

// ---------------- convert W_edge f32 -> packed bf16 (RNE) ----------------
__global__ void conv_bf16(const float* __restrict__ in, unsigned int* __restrict__ outp,
                          int n2) {
    int i = blockIdx.x * 256 + threadIdx.x;
    if (i >= n2) return;
    float2 v = *reinterpret_cast<const float2*>(&in[(long long)i * 2]);
    unsigned int b0 = __float_as_uint(v.x);
    unsigned int b1 = __float_as_uint(v.y);
    b0 = (b0 + 0x7fffu + ((b0 >> 16) & 1u)) >> 16;
    b1 = (b1 + 0x7fffu + ((b1 >> 16) & 1u)) >> 16;
    outp[i] = b0 | (b1 << 16);
}

// ---- merged precompute: blocks 0..127 -> W3 rows; block 128 -> b4 ----
__global__ __launch_bounds__(128) void precompute_all(const float* __restrict__ W_node,
                                                      const float* __restrict__ W_cat2,
                                                      const float* __restrict__ b_edge,
                                                      const float* __restrict__ W_cat1,
                                                      const float* __restrict__ b_node,
                                                      const float* __restrict__ b_cat1,
                                                      const float* __restrict__ b_cat2,
                                                      float* __restrict__ W3,
                                                      float* __restrict__ b4) {
    int c = threadIdx.x;
    if (blockIdx.x < H) {
        int k = blockIdx.x;
        __shared__ float wrow[H];
        wrow[c] = W_node[k * H + c];
        __syncthreads();
        float acc = wrow[c];   // identity part of (I + W_cat2)
        #pragma unroll 8
        for (int j = 0; j < H; ++j)
            acc += wrow[j] * W_cat2[j * H + c];
        W3[k * H + c] = acc;
    } else {
        __shared__ float be[H], bn[H];
        be[c] = b_edge[c];
        bn[c] = b_node[c];
        __syncthreads();
        float acc = be[c] + bn[c] + b_cat1[c] + b_cat2[c];
        for (int j = 0; j < H; ++j)
            acc += be[j] * W_cat1[j * H + c] + bn[j] * W_cat2[j * H + c];
        b4[c] = acc;
    }
}

// ------- fully fused, TR=32 rows/block, 256 threads -------
// Gather: R13 form (per-row CSR walk, bf16 rows, 8 rows/wave).
// Phases B/C: 4 cols x 4 rows per thread (c4=(tid&31)*4, rbase=(tid>>5)*4):
// As/Xs reads become half-wave BROADCASTS (free), LDS read count halves,
// each float4 weight load feeds 16 FMAs -> FMA-pipe-bound.
__global__ __launch_bounds__(256) void gather_fused(const int* __restrict__ off,
                                                    const int* __restrict__ end,
                                                    const int2* __restrict__ csr,
                                                    const unsigned int* __restrict__ wbf,
                                                    const float* __restrict__ x,
                                                    const float* __restrict__ Wc1,
                                                    const float* __restrict__ W3,
                                                    const float* __restrict__ b4,
                                                    const float* __restrict__ Wf,
                                                    const float* __restrict__ bf,
                                                    float* __restrict__ out,
                                                    int nrows) {
    const int TR = 32;
    __shared__ float As[TR][H];
    __shared__ float Xs[TR][H];
    int row0 = blockIdx.x * TR;
    int tid = threadIdx.x;

    // load Xs (x rows): 32*128/4 = 1024 float4 over 256 threads
    for (int i = tid; i < TR * H / 4; i += 256) {
        int fi = i * 4;
        int rr = fi >> 7, cc = fi & 127;
        float4 xv = {0.f, 0.f, 0.f, 0.f};
        if (row0 + rr < nrows)
            xv = *reinterpret_cast<const float4*>(&x[(long long)(row0 + rr) * H + cc]);
        *reinterpret_cast<float4*>(&Xs[rr][cc]) = xv;
    }

    // ---- phase A: gather (bf16 rows). wave w handles rows 8w..8w+7 ----
    int wv = tid >> 6;
    int lane = tid & 63;
    #pragma unroll
    for (int rr8 = 0; rr8 < 8; ++rr8) {
        int rr = wv * 8 + rr8;
        int d = row0 + rr;
        float ax = 0.f, ay = 0.f;
        if (d < nrows) {
            int i0 = __builtin_amdgcn_readfirstlane(off[d]);
            int i1 = __builtin_amdgcn_readfirstlane(end[d]);
            int j = i0;
            for (; j + 4 <= i1; j += 4) {
                int2 e0 = csr[j];
                int2 e1 = csr[j + 1];
                int2 e2 = csr[j + 2];
                int2 e3 = csr[j + 3];
                unsigned int u0 = wbf[(long long)e0.x * 64 + lane];
                unsigned int u1 = wbf[(long long)e1.x * 64 + lane];
                unsigned int u2 = wbf[(long long)e2.x * 64 + lane];
                unsigned int u3 = wbf[(long long)e3.x * 64 + lane];
                float w0 = __int_as_float(e0.y), w1 = __int_as_float(e1.y);
                float w2 = __int_as_float(e2.y), w3 = __int_as_float(e3.y);
                ax += w0 * __uint_as_float(u0 << 16) + w1 * __uint_as_float(u1 << 16)
                    + w2 * __uint_as_float(u2 << 16) + w3 * __uint_as_float(u3 << 16);
                ay += w0 * __uint_as_float(u0 & 0xffff0000u) + w1 * __uint_as_float(u1 & 0xffff0000u)
                    + w2 * __uint_as_float(u2 & 0xffff0000u) + w3 * __uint_as_float(u3 & 0xffff0000u);
            }
            for (; j < i1; ++j) {
                int2 e = csr[j];
                float w = __int_as_float(e.y);
                unsigned int u = wbf[(long long)e.x * 64 + lane];
                ax += w * __uint_as_float(u << 16);
                ay += w * __uint_as_float(u & 0xffff0000u);
            }
        }
        *reinterpret_cast<float2*>(&As[rr][lane * 2]) = make_float2(ax, ay);
    }
    __syncthreads();

    // ---- phase B: t4 = agg + agg@Wc1 + x@W3 + b4 (4 cols x 4 rows/thread) ----
    int c4 = (tid & 31) * 4;
    int rbase = (tid >> 5) * 4;          // 8 groups x 4 rows = 32
    float4 b4v = *reinterpret_cast<const float4*>(&b4[c4]);
    float acc[4][4];
    #pragma unroll
    for (int r = 0; r < 4; ++r) {
        float4 a0 = *reinterpret_cast<const float4*>(&As[rbase + r][c4]);
        acc[r][0] = a0.x + b4v.x;        // identity term of (I + W_cat1)
        acc[r][1] = a0.y + b4v.y;
        acc[r][2] = a0.z + b4v.z;
        acc[r][3] = a0.w + b4v.w;
    }

    for (int k = 0; k < H; k += 4) {
        float4 w1[4], w3[4];
        #pragma unroll
        for (int kk = 0; kk < 4; ++kk) {
            w1[kk] = *reinterpret_cast<const float4*>(&Wc1[(k + kk) * H + c4]);
            w3[kk] = *reinterpret_cast<const float4*>(&W3[(k + kk) * H + c4]);
        }
        #pragma unroll
        for (int r = 0; r < 4; ++r) {
            float4 a  = *reinterpret_cast<const float4*>(&As[rbase + r][k]);   // broadcast
            float4 xv = *reinterpret_cast<const float4*>(&Xs[rbase + r][k]);   // broadcast
            #pragma unroll
            for (int c = 0; c < 4; ++c) {
                float w1c0 = (&w1[0].x)[c], w1c1 = (&w1[1].x)[c],
                      w1c2 = (&w1[2].x)[c], w1c3 = (&w1[3].x)[c];
                float w3c0 = (&w3[0].x)[c], w3c1 = (&w3[1].x)[c],
                      w3c2 = (&w3[2].x)[c], w3c3 = (&w3[3].x)[c];
                acc[r][c] += a.x * w1c0 + a.y * w1c1 + a.z * w1c2 + a.w * w1c3
                           + xv.x * w3c0 + xv.y * w3c1 + xv.z * w3c2 + xv.w * w3c3;
            }
        }
    }

    // ---- relu, stash back to LDS ----
    __syncthreads();
    #pragma unroll
    for (int r = 0; r < 4; ++r) {
        float4 o;
        o.x = fmaxf(acc[r][0], 0.f);
        o.y = fmaxf(acc[r][1], 0.f);
        o.z = fmaxf(acc[r][2], 0.f);
        o.w = fmaxf(acc[r][3], 0.f);
        *reinterpret_cast<float4*>(&As[rbase + r][c4]) = o;
    }
    __syncthreads();

    // ---- phase C: out = relu(t4) @ Wf + bf ----
    float4 bfv = *reinterpret_cast<const float4*>(&bf[c4]);
    float acc2[4][4];
    #pragma unroll
    for (int r = 0; r < 4; ++r) {
        acc2[r][0] = bfv.x;
        acc2[r][1] = bfv.y;
        acc2[r][2] = bfv.z;
        acc2[r][3] = bfv.w;
    }

    for (int k = 0; k < H; k += 4) {
        float4 wf[4];
        #pragma unroll
        for (int kk = 0; kk < 4; ++kk)
            wf[kk] = *reinterpret_cast<const float4*>(&Wf[(k + kk) * H + c4]);
        #pragma unroll
        for (int r = 0; r < 4; ++r) {
            float4 v = *reinterpret_cast<const float4*>(&As[rbase + r][k]);    // broadcast
            #pragma unroll
            for (int c = 0; c < 4; ++c) {
                float wc0 = (&wf[0].x)[c], wc1 = (&wf[1].x)[c],
                      wc2 = (&wf[2].x)[c], wc3 = (&wf[3].x)[c];
                acc2[r][c] += v.x * wc0 + v.y * wc1 + v.z * wc2 + v.w * wc3;
            }
        }
    }

    #pragma unroll
    for (int r = 0; r < 4; ++r) {
        int row = row0 + rbase + r;
        if (row < nrows) {
            float4 o{acc2[r][0], acc2[r][1], acc2[r][2], acc2[r][3]};
            *reinterpret_cast<float4*>(&out[(long long)row * H + c4]) = o;
        }
    }
}

extern "C" void kernel_launch(void* const* d_in, const int* in_sizes, int n_in,
                              void* d_out, int out_size, void* d_ws, size_t ws_size,
                              hipStream_t stream) {
    const float* x       = (const float*)d_in[0];
    const int*   ei      = (const int*)d_in[1];
    const float* ew      = (const float*)d_in[2];
    const float* W_edge  = (const float*)d_in[3];
    const float* b_edge  = (const float*)d_in[4];
    const float* W_node  = (const float*)d_in[5];
    const float* b_node  = (const float*)d_in[6];
    const float* W_cat1  = (const float*)d_in[7];
    const float* b_cat1  = (const float*)d_in[8];
    const float* W_cat2  = (const float*)d_in[9];
    const float* b_cat2  = (const float*)d_in[10];
    const float* W_final = (const float*)d_in[11];
    const float* b_final = (const float*)d_in[12];
    float* out = (float*)d_out;

    // workspace layout
    int*  deg  = (int*)d_ws;                         // NN
    int*  off  = deg + NN;                           // NN
    int*  cur  = off + NN;                           // NN
    int*  sums = cur + NN;                           // 512
    int2* csr  = (int2*)(sums + 512);                // NE   (8B aligned: offset 1202048)
    unsigned int* wbf = (unsigned int*)(csr + NE);   // NN*64 packed bf16 pairs (25.6 MB)
    float* W3  = (float*)(wbf + (size_t)NN * 64);    // H*H
    float* b4  = W3 + H * H;                         // H

    // 1. CSR build
    zero_int<<<(NN + 255) / 256, 256, 0, stream>>>(deg, NN);
    hist_kernel<<<(NE + 255) / 256, 256, 0, stream>>>(ei, deg);
    scan_block<<<NB_SCAN, SCAN_CHUNK, 0, stream>>>(deg, off, sums, NN);
    scan_sums<<<1, 256, 0, stream>>>(sums, NB_SCAN);
    scan_add<<<(NN + 255) / 256, 256, 0, stream>>>(off, sums, cur, NN);
    fill_kernel<<<(NE + 255) / 256, 256, 0, stream>>>(ei, ew, cur, csr);

    // 2. W_edge -> bf16, merged precompute (W3 + b4)
    conv_bf16<<<(NN * H / 2 + 255) / 256, 256, 0, stream>>>(W_edge, wbf, NN * H / 2);
    precompute_all<<<H + 1, H, 0, stream>>>(W_node, W_cat2, b_edge, W_cat1,
                                            b_node, b_cat1, b_cat2, W3, b4);

    // 3. fully fused gather + affine + relu + final linear -> d_out
    gather_fused<<<(NN + 31) / 32, 256, 0, stream>>>(off, cur, csr, wbf, x,
                                                     W_cat1, W3, b4,
                                                     W_final, b_final, out, NN);
}

// Round 15
// 378.624 us; speedup vs baseline: 3.5774x; 1.1750x over previous
//
#include <hip/hip_runtime.h>

#define NN 100000
#define NE 1600000
#define H  128
#define SCAN_CHUNK 512
#define NB_SCAN ((NN + SCAN_CHUNK - 1) / SCAN_CHUNK)   // 196

typedef short short8 __attribute__((ext_vector_type(8)));
typedef float f32x4 __attribute__((ext_vector_type(4)));

__device__ __forceinline__ unsigned short f2bf(float f) {
    unsigned int u = __float_as_uint(f);
    u = (u + 0x7fffu + ((u >> 16) & 1u)) >> 16;
    return (unsigned short)u;
}
__device__ __forceinline__ unsigned int packbf(float a, float b) {
    return (unsigned int)f2bf(a) | ((unsigned int)f2bf(b) << 16);
}

// ---------------- zero int array ----------------
__global__ void zero_int(int* __restrict__ p, int n) {
    int i = blockIdx.x * blockDim.x + threadIdx.x;
    if (i < n) p[i] = 0;
}

// ---------------- histogram of dst ----------------
__global__ void hist_kernel(const int* __restrict__ ei, int* __restrict__ deg) {
    int e = blockIdx.x * 256 + threadIdx.x;
    if (e < NE) atomicAdd(&deg[ei[NE + e]], 1);
}

// ---------------- per-chunk exclusive scan ----------------
__global__ __launch_bounds__(SCAN_CHUNK) void scan_block(const int* __restrict__ deg,
                                                         int* __restrict__ off,
                                                         int* __restrict__ sums, int n) {
    __shared__ int buf[SCAN_CHUNK];
    int base = blockIdx.x * SCAN_CHUNK;
    int t = threadIdx.x;
    int v = (base + t < n) ? deg[base + t] : 0;
    buf[t] = v;
    __syncthreads();
    for (int s = 1; s < SCAN_CHUNK; s <<= 1) {
        int add = (t >= s) ? buf[t - s] : 0;
        __syncthreads();
        buf[t] += add;
        __syncthreads();
    }
    if (base + t < n) off[base + t] = buf[t] - v;
    if (t == SCAN_CHUNK - 1) sums[blockIdx.x] = buf[t];
}

__global__ __launch_bounds__(256) void scan_sums(int* __restrict__ sums, int nb) {
    __shared__ int buf[256];
    int t = threadIdx.x;
    int v = (t < nb) ? sums[t] : 0;
    buf[t] = v;
    __syncthreads();
    for (int s = 1; s < 256; s <<= 1) {
        int add = (t >= s) ? buf[t - s] : 0;
        __syncthreads();
        buf[t] += add;
        __syncthreads();
    }
    if (t < nb) sums[t] = buf[t] - v;
}

__global__ void scan_add(int* __restrict__ off, const int* __restrict__ sums,
                         int* __restrict__ cur, int n) {
    int i = blockIdx.x * 256 + threadIdx.x;
    if (i < n) {
        int v = off[i] + sums[i >> 9];
        off[i] = v;
        cur[i] = v;
    }
}

// ---------------- fill CSR with packed (src, weight) ----------------
__global__ void fill_kernel(const int* __restrict__ ei, const float* __restrict__ ew,
                            int* __restrict__ cur, int2* __restrict__ csr) {
    int e = blockIdx.x * 256 + threadIdx.x;
    if (e >= NE) return;
    int d = ei[NE + e];
    int pos = atomicAdd(&cur[d], 1);
    csr[pos] = make_int2(ei[e], __float_as_int(ew[e]));
}

// ---------------- convert W_edge f32 -> packed bf16 (RNE) ----------------
__global__ void conv_bf16(const float* __restrict__ in, unsigned int* __restrict__ outp,
                          int n2) {
    int i = blockIdx.x * 256 + threadIdx.x;
    if (i >= n2) return;
    float2 v = *reinterpret_cast<const float2*>(&in[(long long)i * 2]);
    outp[i] = packbf(v.x, v.y);
}

// ---- prep_weights: blocks 0..127 -> wcat_t/wf_t row n (transposed bf16); block 128 -> b4 ----
// wcat_t[n][k] (k<128: (I+Wc1)[k][n], k>=128: W3[k-128][n]), W3 = W_node @ (I + W_cat2).
__global__ __launch_bounds__(128) void prep_weights(const float* __restrict__ W_node,
                                                    const float* __restrict__ W_cat1,
                                                    const float* __restrict__ W_cat2,
                                                    const float* __restrict__ W_final,
                                                    const float* __restrict__ b_edge,
                                                    const float* __restrict__ b_node,
                                                    const float* __restrict__ b_cat1,
                                                    const float* __restrict__ b_cat2,
                                                    unsigned short* __restrict__ wcat_t,
                                                    unsigned short* __restrict__ wf_t,
                                                    float* __restrict__ b4) {
    int t = threadIdx.x;
    int n = blockIdx.x;
    if (n < H) {
        __shared__ float c2col[H];
        c2col[t] = W_cat2[t * H + n];
        __syncthreads();
        float dot = 0.f;
        #pragma unroll 8
        for (int j = 0; j < H; ++j)
            dot += W_node[t * H + j] * c2col[j];
        float w3 = W_node[t * H + n] + dot;
        wcat_t[n * 256 + t]       = f2bf(W_cat1[t * H + n] + (t == n ? 1.f : 0.f));
        wcat_t[n * 256 + 128 + t] = f2bf(w3);
        wf_t[n * 128 + t]         = f2bf(W_final[t * H + n]);
    } else {
        __shared__ float be[H], bn[H];
        be[t] = b_edge[t];
        bn[t] = b_node[t];
        __syncthreads();
        float acc = be[t] + bn[t] + b_cat1[t] + b_cat2[t];
        for (int j = 0; j < H; ++j)
            acc += be[j] * W_cat1[j * H + t] + bn[j] * W_cat2[j * H + t];
        b4[t] = acc;
    }
}

// ------- fully fused, TR=32: gather(bf16) + MFMA B (K=256) + relu + MFMA C -------
// LDS tiles stored bf16-packed with T2 XOR swizzle (idx ^ (row&7) on 16B units).
// A-frag: row=lane&15, k=(lane>>4)*8+e. B-frag from transposed bf16 weights (16B loads).
// C/D: col=lane&15, row=(lane>>4)*4+reg [m89].
__global__ __launch_bounds__(256) void gather_fused(const int* __restrict__ off,
                                                    const int* __restrict__ end,
                                                    const int2* __restrict__ csr,
                                                    const unsigned int* __restrict__ wbf,
                                                    const float* __restrict__ x,
                                                    const unsigned short* __restrict__ wcat_t,
                                                    const float* __restrict__ b4,
                                                    const unsigned short* __restrict__ wf_t,
                                                    const float* __restrict__ bf,
                                                    float* __restrict__ out,
                                                    int nrows) {
    const int TR = 32;
    __shared__ unsigned int Asb[TR][64];   // bf16x2, swizzled
    __shared__ unsigned int Xsb[TR][64];   // bf16x2, swizzled
    __shared__ unsigned int T4b[TR][64];   // bf16x2, swizzled
    int row0 = blockIdx.x * TR;
    int tid = threadIdx.x;

    // load Xs -> bf16 packed, swizzled
    for (int i = tid; i < TR * H / 4; i += 256) {
        int fi = i * 4;
        int rr = fi >> 7, cc = fi & 127;
        float4 xv = {0.f, 0.f, 0.f, 0.f};
        if (row0 + rr < nrows)
            xv = *reinterpret_cast<const float4*>(&x[(long long)(row0 + rr) * H + cc]);
        int sw = (rr & 7) << 2;
        Xsb[rr][(cc >> 1) ^ sw]       = packbf(xv.x, xv.y);
        Xsb[rr][((cc >> 1) + 1) ^ sw] = packbf(xv.z, xv.w);
    }

    // ---- phase A: gather (bf16 rows). wave w handles rows 8w..8w+7 ----
    int wv = tid >> 6;
    int lane = tid & 63;
    #pragma unroll
    for (int rr8 = 0; rr8 < 8; ++rr8) {
        int rr = wv * 8 + rr8;
        int d = row0 + rr;
        float ax = 0.f, ay = 0.f;
        if (d < nrows) {
            int i0 = __builtin_amdgcn_readfirstlane(off[d]);
            int i1 = __builtin_amdgcn_readfirstlane(end[d]);
            int j = i0;
            for (; j + 4 <= i1; j += 4) {
                int2 e0 = csr[j];
                int2 e1 = csr[j + 1];
                int2 e2 = csr[j + 2];
                int2 e3 = csr[j + 3];
                unsigned int u0 = wbf[(long long)e0.x * 64 + lane];
                unsigned int u1 = wbf[(long long)e1.x * 64 + lane];
                unsigned int u2 = wbf[(long long)e2.x * 64 + lane];
                unsigned int u3 = wbf[(long long)e3.x * 64 + lane];
                float w0 = __int_as_float(e0.y), w1 = __int_as_float(e1.y);
                float w2 = __int_as_float(e2.y), w3 = __int_as_float(e3.y);
                ax += w0 * __uint_as_float(u0 << 16) + w1 * __uint_as_float(u1 << 16)
                    + w2 * __uint_as_float(u2 << 16) + w3 * __uint_as_float(u3 << 16);
                ay += w0 * __uint_as_float(u0 & 0xffff0000u) + w1 * __uint_as_float(u1 & 0xffff0000u)
                    + w2 * __uint_as_float(u2 & 0xffff0000u) + w3 * __uint_as_float(u3 & 0xffff0000u);
            }
            for (; j < i1; ++j) {
                int2 e = csr[j];
                float w = __int_as_float(e.y);
                unsigned int u = wbf[(long long)e.x * 64 + lane];
                ax += w * __uint_as_float(u << 16);
                ay += w * __uint_as_float(u & 0xffff0000u);
            }
        }
        Asb[rr][lane ^ ((rr & 7) << 2)] = packbf(ax, ay);
    }
    __syncthreads();

    // ---- phase B: t4 = [agg|x] @ wcat + b4, via MFMA (K=256, 8 steps) ----
    int rt  = wv & 1;                 // row-tile 0..1
    int ctb = (tid >> 7) * 4;         // col-tile base: 0 or 4
    int l15 = lane & 15, lhi = lane >> 4;
    int arow = rt * 16 + l15;
    int asw  = arow & 7;              // short8-level swizzle for this lane's row

    f32x4 zero4 = {0.f, 0.f, 0.f, 0.f};
    f32x4 acc[4];
    acc[0] = zero4; acc[1] = zero4; acc[2] = zero4; acc[3] = zero4;

    const short8* asrow = reinterpret_cast<const short8*>(&Asb[arow][0]);
    const short8* xsrow = reinterpret_cast<const short8*>(&Xsb[arow][0]);

    #pragma unroll
    for (int kt = 0; kt < 8; ++kt) {
        short8 afrag = (kt < 4) ? asrow[(kt * 4 + lhi) ^ asw]
                                : xsrow[((kt - 4) * 4 + lhi) ^ asw];
        #pragma unroll
        for (int j = 0; j < 4; ++j) {
            int ct = ctb + j;
            short8 bfrag = *reinterpret_cast<const short8*>(
                &wcat_t[(ct * 16 + l15) * 256 + kt * 32 + lhi * 8]);
            acc[j] = __builtin_amdgcn_mfma_f32_16x16x32_bf16(afrag, bfrag, acc[j], 0, 0, 0);
        }
    }

    // epilogue B: +b4, relu, store bf16 to T4 (swizzled)
    unsigned short* t4s = reinterpret_cast<unsigned short*>(T4b);
    #pragma unroll
    for (int j = 0; j < 4; ++j) {
        int colg = (ctb + j) * 16 + l15;
        float bv = b4[colg];
        #pragma unroll
        for (int r = 0; r < 4; ++r) {
            int row = rt * 16 + lhi * 4 + r;
            float v = fmaxf(acc[j][r] + bv, 0.f);
            t4s[row * 128 + (colg ^ ((row & 7) << 3))] = f2bf(v);
        }
    }
    __syncthreads();

    // ---- phase C: out = relu(t4) @ wf + bf, via MFMA (K=128, 4 steps) ----
    f32x4 acc2[4];
    acc2[0] = zero4; acc2[1] = zero4; acc2[2] = zero4; acc2[3] = zero4;
    const short8* t4row = reinterpret_cast<const short8*>(&T4b[arow][0]);

    #pragma unroll
    for (int kt = 0; kt < 4; ++kt) {
        short8 afrag = t4row[(kt * 4 + lhi) ^ asw];
        #pragma unroll
        for (int j = 0; j < 4; ++j) {
            int ct = ctb + j;
            short8 bfrag = *reinterpret_cast<const short8*>(
                &wf_t[(ct * 16 + l15) * 128 + kt * 32 + lhi * 8]);
            acc2[j] = __builtin_amdgcn_mfma_f32_16x16x32_bf16(afrag, bfrag, acc2[j], 0, 0, 0);
        }
    }

    #pragma unroll
    for (int j = 0; j < 4; ++j) {
        int colg = (ctb + j) * 16 + l15;
        float bv = bf[colg];
        #pragma unroll
        for (int r = 0; r < 4; ++r) {
            int row = row0 + rt * 16 + lhi * 4 + r;
            if (row < nrows)
                out[(long long)row * H + colg] = acc2[j][r] + bv;
        }
    }
}

extern "C" void kernel_launch(void* const* d_in, const int* in_sizes, int n_in,
                              void* d_out, int out_size, void* d_ws, size_t ws_size,
                              hipStream_t stream) {
    const float* x       = (const float*)d_in[0];
    const int*   ei      = (const int*)d_in[1];
    const float* ew      = (const float*)d_in[2];
    const float* W_edge  = (const float*)d_in[3];
    const float* b_edge  = (const float*)d_in[4];
    const float* W_node  = (const float*)d_in[5];
    const float* b_node  = (const float*)d_in[6];
    const float* W_cat1  = (const float*)d_in[7];
    const float* b_cat1  = (const float*)d_in[8];
    const float* W_cat2  = (const float*)d_in[9];
    const float* b_cat2  = (const float*)d_in[10];
    const float* W_final = (const float*)d_in[11];
    const float* b_final = (const float*)d_in[12];
    float* out = (float*)d_out;

    // workspace layout
    int*  deg  = (int*)d_ws;                           // NN
    int*  off  = deg + NN;                             // NN
    int*  cur  = off + NN;                             // NN
    int*  sums = cur + NN;                             // 512
    int2* csr  = (int2*)(sums + 512);                  // NE (8B aligned)
    unsigned int* wbf = (unsigned int*)(csr + NE);     // NN*64 packed bf16 pairs (25.6 MB)
    unsigned short* wcat_t = (unsigned short*)(wbf + (size_t)NN * 64);  // 128*256 (64 KB)
    unsigned short* wf_t   = wcat_t + 256 * H;                          // 128*128 (32 KB)
    float* b4 = (float*)(wf_t + H * H);                                 // 128

    // 1. CSR build
    zero_int<<<(NN + 255) / 256, 256, 0, stream>>>(deg, NN);
    hist_kernel<<<(NE + 255) / 256, 256, 0, stream>>>(ei, deg);
    scan_block<<<NB_SCAN, SCAN_CHUNK, 0, stream>>>(deg, off, sums, NN);
    scan_sums<<<1, 256, 0, stream>>>(sums, NB_SCAN);
    scan_add<<<(NN + 255) / 256, 256, 0, stream>>>(off, sums, cur, NN);
    fill_kernel<<<(NE + 255) / 256, 256, 0, stream>>>(ei, ew, cur, csr);

    // 2. W_edge -> bf16; transposed bf16 weights + b4
    conv_bf16<<<(NN * H / 2 + 255) / 256, 256, 0, stream>>>(W_edge, wbf, NN * H / 2);
    prep_weights<<<H + 1, H, 0, stream>>>(W_node, W_cat1, W_cat2, W_final,
                                          b_edge, b_node, b_cat1, b_cat2,
                                          wcat_t, wf_t, b4);

    // 3. fully fused gather + MFMA affine + relu + MFMA final -> d_out
    gather_fused<<<(NN + 31) / 32, 256, 0, stream>>>(off, cur, csr, wbf, x,
                                                     wcat_t, b4, wf_t, b_final,
                                                     out, NN);
}